// Round 3
// baseline (1940.630 us; speedup 1.0000x reference)
//
#include <hip/hip_runtime.h>

#define NUSERS 100000
#define NITEMS 50000
#define NNODES 150000
#define HID    128
#define NEDGE  1000000

typedef unsigned int u32;
typedef unsigned short u16;

__device__ __forceinline__ float bflo(u32 u){ return __uint_as_float(u << 16); }
__device__ __forceinline__ float bfhi(u32 u){ return __uint_as_float(u & 0xFFFF0000u); }
// pack two fp32 into bf16x2 (RNE)
__device__ __forceinline__ u32 packbf2(float a, float b){
  u32 ua = __float_as_uint(a), ub = __float_as_uint(b);
  ua += 0x7FFFu + ((ua >> 16) & 1u);
  ub += 0x7FFFu + ((ub >> 16) & 1u);
  return (ua >> 16) | (ub & 0xFFFF0000u);
}

__global__ __launch_bounds__(256) void k_zero(int* __restrict__ p, int n){
  int i = blockIdx.x * 256 + threadIdx.x;
  if (i < n) p[i] = 0;
}

__global__ __launch_bounds__(256) void k_deg(const int* __restrict__ uidx,
                                             const int* __restrict__ iidx,
                                             int* __restrict__ deg){
  int e = blockIdx.x * 256 + threadIdx.x;
  if (e < NEDGE){
    atomicAdd(&deg[uidx[e]], 1);
    atomicAdd(&deg[NUSERS + iidx[e]], 1);
  }
}

__global__ __launch_bounds__(256) void k_dinv(const int* __restrict__ deg,
                                              float* __restrict__ dinv){
  int n = blockIdx.x * 256 + threadIdx.x;
  if (n < NNODES) dinv[n] = rsqrtf(fmaxf((float)deg[n], 1.0f));
}

// ---- 3-kernel exclusive scan of deg -> rp (tile = 1024) ----
__global__ __launch_bounds__(256) void k_scan1(const int* __restrict__ deg,
                                               int* __restrict__ rp,
                                               int* __restrict__ part){
  __shared__ int sm[256];
  int t = threadIdx.x;
  int base = blockIdx.x * 1024 + t * 4;
  int v0 = (base + 0 < NNODES) ? deg[base + 0] : 0;
  int v1 = (base + 1 < NNODES) ? deg[base + 1] : 0;
  int v2 = (base + 2 < NNODES) ? deg[base + 2] : 0;
  int v3 = (base + 3 < NNODES) ? deg[base + 3] : 0;
  sm[t] = v0 + v1 + v2 + v3;
  __syncthreads();
  for (int off = 1; off < 256; off <<= 1){
    int x = (t >= off) ? sm[t - off] : 0;
    __syncthreads();
    sm[t] += x;
    __syncthreads();
  }
  if (t == 255) part[blockIdx.x] = sm[255];
  int run = (t > 0) ? sm[t - 1] : 0;
  if (base + 0 < NNODES) rp[base + 0] = run;
  run += v0;
  if (base + 1 < NNODES) rp[base + 1] = run;
  run += v1;
  if (base + 2 < NNODES) rp[base + 2] = run;
  run += v2;
  if (base + 3 < NNODES) rp[base + 3] = run;
}

__global__ __launch_bounds__(256) void k_scan2(int* __restrict__ part, int nb){
  __shared__ int sm[256];
  int t = threadIdx.x;
  sm[t] = (t < nb) ? part[t] : 0;
  __syncthreads();
  for (int off = 1; off < 256; off <<= 1){
    int x = (t >= off) ? sm[t - off] : 0;
    __syncthreads();
    sm[t] += x;
    __syncthreads();
  }
  int excl = (t > 0) ? sm[t - 1] : 0;
  if (t < nb) part[t] = excl;
}

__global__ __launch_bounds__(256) void k_scan3(int* __restrict__ rp,
                                               const int* __restrict__ part){
  int i = blockIdx.x * 256 + threadIdx.x;
  if (i < NNODES) rp[i] += part[i >> 10];
}

// place both directed edges into CSR-by-dst; payload = src | (t<<18)
__global__ __launch_bounds__(256) void k_place(const int* __restrict__ uidx,
                                               const int* __restrict__ iidx,
                                               const int* __restrict__ tseq,
                                               const int* __restrict__ rp,
                                               int* __restrict__ cursor,
                                               u32* __restrict__ edges){
  int e = blockIdx.x * 256 + threadIdx.x;
  if (e >= NEDGE) return;
  int u  = uidx[e];
  int it = NUSERS + iidx[e];
  u32 tb = ((u32)tseq[e]) << 18;
  int p1 = rp[it] + atomicAdd(&cursor[it], 1);  // dst = item, src = user
  edges[p1] = (u32)u | tb;
  int p2 = rp[u] + atomicAdd(&cursor[u], 1);    // dst = user, src = item
  edges[p2] = (u32)it | tb;
}

// x0[n] <- bf16(concat(ue,ie)[n]); out cols [0:128) <- fp32 raw embeddings
__global__ __launch_bounds__(256) void k_init(const float* __restrict__ ue,
                                              const float* __restrict__ ie,
                                              u32* __restrict__ x,
                                              float* __restrict__ out){
  int tid = blockIdx.x * 256 + threadIdx.x;
  int n = tid >> 6, L = tid & 63;
  if (n >= NNODES) return;
  const float* src = (n < NUSERS) ? ue + (size_t)n * HID
                                  : ie + (size_t)(n - NUSERS) * HID;
  float2 v = ((const float2*)src)[L];
  x[(size_t)n * 64 + L] = packbf2(v.x, v.y);
  ((float2*)(out + (size_t)n * 512))[L] = v;
}

// Fused layer: 512 threads = 8 waves = 8 nodes/block.
//   agg = dinv[n] * sum_e dinv[src]*(xin[src]+tt[t])  (fp32 acc; xin bf16, tt fp32)
//   h   = leaky(agg @ W + b)  (W fp32 in LDS; agg row in per-wave LDS)
//   xout <- bf16(h);  out[:, colOff:colOff+128] <- fp32 l2norm(h)
__global__ __launch_bounds__(512) void k_layer(
    const u32* __restrict__ xin,   // bf16x2 packed [NNODES][64]
    const float* __restrict__ tt,  // [512][128]
    const float* __restrict__ dinv,
    const int* __restrict__ rp,
    const int* __restrict__ deg,
    const u32* __restrict__ edges,
    const float* __restrict__ Wl,  // [128][128] row-major (k, col)
    const float* __restrict__ bl,  // [128]
    u32* __restrict__ xout,
    float* __restrict__ out,       // [NNODES][512]
    int colOff)
{
  __shared__ float Ws[HID * HID];   // 64 KB
  __shared__ float aggS[8][HID];    // 4 KB
  {
    const float4* Wg = (const float4*)Wl;
    float4* Wv = (float4*)Ws;
    #pragma unroll
    for (int i = 0; i < 8; i++) Wv[threadIdx.x + 512 * i] = Wg[threadIdx.x + 512 * i];
  }
  __syncthreads();

  int wv = threadIdx.x >> 6;
  int L  = threadIdx.x & 63;
  int n  = blockIdx.x * 8 + wv;   // grid exact -> always valid

  int start = rp[n];
  int cnt   = deg[n];
  float a0 = 0.f, a1 = 0.f;
  for (int base = 0; base < cnt; base += 64){
    u32 pe = 0xFFFFFFFFu;                       // fails guard if out of range
    if (base + L < cnt) pe = edges[start + base + L];
    int m = cnt - base; if (m > 64) m = 64;
    for (int j = 0; j < m; j++){
      u32 p = __shfl(pe, j);
      u32 s = p & 0x3FFFFu;
      u32 t = p >> 18;
      if (s < (u32)NNODES && t < 512u){         // no-op if CSR correct
        float c = dinv[s];
        u32 xv = xin[(size_t)s * 64 + L];
        float2 tv = ((const float2*)(tt + (size_t)t * HID))[L];
        a0 = fmaf(bflo(xv) + tv.x, c, a0);
        a1 = fmaf(bfhi(xv) + tv.y, c, a1);
      }
    }
  }
  float sc = dinv[n];
  aggS[wv][2 * L]     = a0 * sc;
  aggS[wv][2 * L + 1] = a1 * sc;
  // no barrier: each wave reads only its own aggS row (same-wave DS order)

  float acc0 = 0.f, acc1 = 0.f;
  #pragma unroll 4
  for (int k = 0; k < HID; k++){
    float a = aggS[wv][k];                      // broadcast read
    float2 w2 = ((const float2*)(Ws + k * HID))[L];
    acc0 = fmaf(a, w2.x, acc0);
    acc1 = fmaf(a, w2.y, acc1);
  }
  float2 bb = ((const float2*)bl)[L];
  acc0 += bb.x;
  acc1 += bb.y;
  acc0 = (acc0 > 0.f) ? acc0 : 0.2f * acc0;
  acc1 = (acc1 > 0.f) ? acc1 : 0.2f * acc1;

  xout[(size_t)n * 64 + L] = packbf2(acc0, acc1);  // unnormalized h -> next layer

  float ss = fmaf(acc0, acc0, acc1 * acc1);
  #pragma unroll
  for (int off = 1; off < 64; off <<= 1) ss += __shfl_xor(ss, off);
  float inv = 1.0f / fmaxf(sqrtf(ss), 1e-12f);
  float2 o;
  o.x = acc0 * inv;
  o.y = acc1 * inv;
  ((float2*)(out + (size_t)n * 512 + colOff))[L] = o;
}

extern "C" void kernel_launch(void* const* d_in, const int* in_sizes, int n_in,
                              void* d_out, int out_size, void* d_ws, size_t ws_size,
                              hipStream_t stream){
  const float* ue = (const float*)d_in[0];  // [100000,128] fp32
  const float* ie = (const float*)d_in[1];  // [50000,128]  fp32
  const float* tt = (const float*)d_in[2];  // [512,128]    fp32
  const float* W  = (const float*)d_in[3];  // [3,128,128]  fp32
  const float* b  = (const float*)d_in[4];  // [3,128]      fp32
  const int* uidx = (const int*)d_in[5];
  const int* iidx = (const int*)d_in[6];
  const int* tseq = (const int*)d_in[7];
  float* out = (float*)d_out;               // [150000,512] fp32

  char* wsp = (char*)d_ws;
  size_t off = 0;
  auto alloc = [&](size_t bytes) -> void* {
    void* p = wsp + off;
    off = (off + bytes + 255) & ~(size_t)255;
    return p;
  };
  int*   deg    = (int*)  alloc((size_t)NNODES * 4);
  float* dinv   = (float*)alloc((size_t)NNODES * 4);
  int*   rp     = (int*)  alloc((size_t)NNODES * 4);
  int*   part   = (int*)  alloc(256 * 4);
  int*   cursor = (int*)  alloc((size_t)NNODES * 4);
  u32*   edges  = (u32*)  alloc((size_t)2 * NEDGE * 4);
  u32*   x0     = (u32*)  alloc((size_t)NNODES * 64 * 4);  // bf16x2 packed
  u32*   x1     = (u32*)  alloc((size_t)NNODES * 64 * 4);
  // total ws use: ~87.2 MB

  const int nbN = (NNODES + 255) / 256;     // 587
  const int nbE = (NEDGE + 255) / 256;      // 3907
  const int nbT = (NNODES + 1023) / 1024;   // 147
  const int nbI = NNODES * 64 / 256;        // 37500 (exact)
  const int nbL = NNODES / 8;               // 18750 (exact)

  k_zero<<<nbN, 256, 0, stream>>>(deg, NNODES);
  k_zero<<<nbN, 256, 0, stream>>>(cursor, NNODES);
  k_deg<<<nbE, 256, 0, stream>>>(uidx, iidx, deg);
  k_dinv<<<nbN, 256, 0, stream>>>(deg, dinv);
  k_scan1<<<nbT, 256, 0, stream>>>(deg, rp, part);
  k_scan2<<<1, 256, 0, stream>>>(part, nbT);
  k_scan3<<<nbN, 256, 0, stream>>>(rp, part);
  k_place<<<nbE, 256, 0, stream>>>(uidx, iidx, tseq, rp, cursor, edges);
  k_init<<<nbI, 256, 0, stream>>>(ue, ie, x0, out);

  k_layer<<<nbL, 512, 0, stream>>>(x0, tt, dinv, rp, deg, edges,
                                   W + 0 * HID * HID, b + 0 * HID, x1, out, 1 * HID);
  k_layer<<<nbL, 512, 0, stream>>>(x1, tt, dinv, rp, deg, edges,
                                   W + 1 * HID * HID, b + 1 * HID, x0, out, 2 * HID);
  k_layer<<<nbL, 512, 0, stream>>>(x0, tt, dinv, rp, deg, edges,
                                   W + 2 * HID * HID, b + 2 * HID, x1, out, 3 * HID);
}